// Round 1
// baseline (85691.150 us; speedup 1.0000x reference)
//
#include <hip/hip_runtime.h>
#include <stdint.h>

#define TT 8192
#define NN 512
#define MM 2048
#define KK 3
#define RHO_C 1e-4f
#define NWG 256
#define NTHR 512

__device__ __forceinline__ unsigned long long pack_eh(unsigned int e, float v) {
    union { float f; unsigned int u; } c; c.f = v;
    return ((unsigned long long)e << 32) | (unsigned long long)c.u;
}

// Persistent kernel: one WG per CU, WG wg owns output rows [8*wg, 8*wg+8).
// Wave w (64 lanes) owns row 8*wg+w; lane holds M cols c = lane + 64*cb (cb<32)
// and A' cols j = lane + 64*m (m<8), all in registers.
__global__ __launch_bounds__(NTHR, 2)
void lista_persist(const float* __restrict__ x,      // [T, N]
                   const float* __restrict__ A,      // [K, M, N]
                   const float* __restrict__ alpha,  // [K+1]
                   const float* __restrict__ h0,     // [M]
                   float* __restrict__ out,          // [T, M]
                   unsigned long long* __restrict__ hbuf) // ws: [2][M] epoch-tagged
{
    const int wg   = blockIdx.x;
    const int tid  = threadIdx.x;
    const int w    = tid >> 6;     // wave id 0..7
    const int lane = tid & 63;
    const int row  = wg * 8 + w;

    __shared__ float At[4][MM];      // 32 KB: A^T chunk  At[jj][c] = A[k][c][jc*4+jj]
    __shared__ float Aplds[8][NN];   // 16 KB: this wave's scaled A row (broadcast reads)
    __shared__ float lds_h[MM];      //  8 KB
    __shared__ float lds_x[NN];      //  2 KB

    float inva[KK], rhoa[KK];
#pragma unroll
    for (int k = 0; k < KK; ++k) {
        float a = alpha[k + 1];
        inva[k] = 1.0f / a;
        rhoa[k] = RHO_C / a;
    }

    // A'_k row of this wave in regs: a2[k][m] = A[k][row][lane+64m] / a_k
    float a2[KK][8];
#pragma unroll
    for (int k = 0; k < KK; ++k) {
        const float* Ar = A + ((size_t)k * MM + row) * NN;
#pragma unroll
        for (int m = 0; m < 8; ++m) a2[k][m] = Ar[lane + 64 * m] * inva[k];
    }

    // ---------------- init: M_k rows into registers ----------------
    // mr[k][cb] accumulates B[row,c]/a = sum_j (A[row,j]/a) * A[c,j], c = lane+64cb
    float mr[KK][32];
#pragma unroll
    for (int k = 0; k < KK; ++k)
#pragma unroll
        for (int cb = 0; cb < 32; ++cb) mr[k][cb] = 0.0f;

#pragma unroll
    for (int k = 0; k < KK; ++k) {
        // stage this wave's scaled A row for runtime-indexed broadcast reads
#pragma unroll
        for (int m = 0; m < 8; ++m) Aplds[w][lane + 64 * m] = a2[k][m];
        const float* Ak = A + (size_t)k * MM * NN;
        for (int jc = 0; jc < 128; ++jc) {   // 4-wide j chunks
            __syncthreads();                  // prior chunk's reads done
            // stage At[jj][c] = A[k][c][jc*4+jj], 512 threads x 4 rows each
#pragma unroll
            for (int cc = 0; cc < 4; ++cc) {
                int c = tid + 512 * cc;
                const float4 v = *(const float4*)(Ak + (size_t)c * NN + jc * 4);
                At[0][c] = v.x; At[1][c] = v.y; At[2][c] = v.z; At[3][c] = v.w;
            }
            __syncthreads();
#pragma unroll
            for (int jj = 0; jj < 4; ++jj) {
                float s = Aplds[w][jc * 4 + jj];   // broadcast (same addr all lanes)
#pragma unroll
                for (int cb = 0; cb < 32; ++cb)
                    mr[k][cb] += s * At[jj][lane + 64 * cb];  // 2-way bank alias: free
            }
        }
        __syncthreads();
    }
    // finalize M = I - B/a
#pragma unroll
    for (int k = 0; k < KK; ++k)
#pragma unroll
        for (int cb = 0; cb < 32; ++cb) {
            float d = (lane + 64 * cb == row) ? 1.0f : 0.0f;
            mr[k][cb] = d - mr[k][cb];
        }

    // publish h0 as epoch 0 into parity buffer 0 (ws poison 0xAAAAAAAA never == epoch)
    if (lane == 0)
        __hip_atomic_store(&hbuf[row], pack_eh(0u, h0[row]),
                           __ATOMIC_RELAXED, __HIP_MEMORY_SCOPE_AGENT);

    // ---------------- sequential scan ----------------
    unsigned int e = 0;   // epoch of current h state; matvec (t,k) consumes e, produces e+1
    for (int t = 0; t < TT; ++t) {
        __syncthreads();                          // all waves done with lds_x
        lds_x[tid] = x[(size_t)t * NN + tid];     // NTHR == NN
#pragma unroll
        for (int k = 0; k < KK; ++k) {
            __syncthreads();                      // all waves done reading lds_h
            unsigned long long* src = hbuf + (size_t)(e & 1) * MM;
            bool ok[4] = {false, false, false, false};
            int done;
            do {
                int all = 1;
#pragma unroll
                for (int j = 0; j < 4; ++j) {
                    if (!ok[j]) {
                        int ent = tid + 512 * j;
                        unsigned long long v = __hip_atomic_load(
                            &src[ent], __ATOMIC_RELAXED, __HIP_MEMORY_SCOPE_AGENT);
                        if ((unsigned int)(v >> 32) == e) {
                            lds_h[ent] = __uint_as_float((unsigned int)v);
                            ok[j] = true;
                        } else {
                            all = 0;
                        }
                    }
                }
                done = __syncthreads_and(all);
                if (!done) __builtin_amdgcn_s_sleep(2);   // ~128 cy backoff
            } while (!done);

            // v = M_k[row,:] @ h + (A_k[row,:]/a) @ x_t
            float p = 0.0f;
#pragma unroll
            for (int cb = 0; cb < 32; ++cb) p += mr[k][cb] * lds_h[lane + 64 * cb];
#pragma unroll
            for (int m = 0; m < 8; ++m)  p += a2[k][m] * lds_x[lane + 64 * m];
#pragma unroll
            for (int s = 1; s < 64; s <<= 1) p += __shfl_xor(p, s, 64);
            float hn = fmaxf(p - rhoa[k], 0.0f);  // shrink+relu collapses to this
            ++e;
            if (lane == 0) {
                __hip_atomic_store(&hbuf[(size_t)(e & 1) * MM + row], pack_eh(e, hn),
                                   __ATOMIC_RELAXED, __HIP_MEMORY_SCOPE_AGENT);
                if (k == KK - 1) out[(size_t)t * MM + row] = hn;
            }
        }
    }
}

extern "C" void kernel_launch(void* const* d_in, const int* in_sizes, int n_in,
                              void* d_out, int out_size, void* d_ws, size_t ws_size,
                              hipStream_t stream) {
    const float* x     = (const float*)d_in[0];
    const float* A     = (const float*)d_in[1];
    const float* alpha = (const float*)d_in[2];
    const float* h0    = (const float*)d_in[3];
    float* out = (float*)d_out;
    unsigned long long* hbuf = (unsigned long long*)d_ws;  // 2*2048*8 = 32 KB

    hipLaunchKernelGGL(lista_persist, dim3(NWG), dim3(NTHR), 0, stream,
                       x, A, alpha, h0, out, hbuf);
}